// Round 6
// baseline (56.834 us; speedup 1.0000x reference)
//
#include <hip/hip_runtime.h>

#define NROWS 4096
#define NCOLS 4096
#define TPB   256

// Global coeff row layout (floats):
// [det0 2048 | det1 1024 | det2 512 | det3 256 | det4 128 | det5 64 | det6 32 | det7 16 | a7 16]
// LDS: P0[2048], P1[2048], Csm[512] (dets 3..7 + a7 mirror).

#define LD4(arr, base, vec) { float4 _v = (vec); (arr)[(base)] = _v.x; (arr)[(base)+1] = _v.y; (arr)[(base)+2] = _v.z; (arr)[(base)+3] = _v.w; }
#define LD2(arr, base, vec) { float2 _v = (vec); (arr)[(base)] = _v.x; (arr)[(base)+1] = _v.y; }

// Wave-synchronous LDS fence (rule #18): drain DS ops, pin the scheduler.
#define WAVE_FENCE() do { asm volatile("s_waitcnt lgkmcnt(0)" ::: "memory"); \
                          __builtin_amdgcn_sched_barrier(0); } while (0)

// stride-1 taps: E/O are separate (deinterleaved) arrays
__device__ __forceinline__ void fwd_pt(const float* e8, const float* o8,
                                       const float* wl, float& dd, float& aa)
{
    float d = 0.f, a = 0.f;
    #pragma unroll
    for (int t = 0; t < 8; ++t) {
        float e = e8[-t], o = o8[-t];
        d = fmaf(wl[2*t],     e, d);
        d = fmaf(wl[2*t+1],   o, d);
        a = fmaf(wl[15-2*t],  e, a);
        a = fmaf(-wl[14-2*t], o, a);
    }
    dd = d; aa = a;
}

// stride-2 taps: window is the RAW interleaved x row (E[k-t]=x[2(k-t)])
__device__ __forceinline__ void fwd_pt2(const float* e8, const float* o8,
                                        const float* wl, float& dd, float& aa)
{
    float d = 0.f, a = 0.f;
    #pragma unroll
    for (int t = 0; t < 8; ++t) {
        float e = e8[-2*t], o = o8[-2*t];
        d = fmaf(wl[2*t],     e, d);
        d = fmaf(wl[2*t+1],   o, d);
        a = fmaf(wl[15-2*t],  e, a);
        a = fmaf(-wl[14-2*t], o, a);
    }
    dd = d; aa = a;
}

__device__ __forceinline__ void bwd_pt(const float* d8, const float* a8,
                                       const float* wl, float& rr0, float& rr1)
{
    float x = 0.f, y = 0.f;
    #pragma unroll
    for (int t = 0; t < 8; ++t) {
        float dv = d8[-t], av = a8[-t];
        x = fmaf(wl[15-2*t], dv, x);
        x = fmaf(wl[2*t],    av, x);
        y = fmaf(wl[14-2*t], dv, y);
        y = fmaf(-wl[2*t+1], av, y);
    }
    rr0 = x; rr1 = y;
}

__global__ __launch_bounds__(TPB, 6) void despawn_kernel(
    const float* __restrict__ in, const float* __restrict__ wv,
    float* __restrict__ out_rec, float* __restrict__ out_coef)
{
    __shared__ float P0[2048];
    __shared__ float P1[2048];
    __shared__ float Csm[512];

    const int tid = threadIdx.x;
    const int row = blockIdx.x;
    const float* rowIn = in + (size_t)row * NCOLS;
    float* crow = out_coef + (size_t)row * NCOLS;
    float* rrow = out_rec  + (size_t)row * NCOLS;

    float wl[16];

    // ===== fwd level 0: global x -> det0(global), E1->P0[0..1023], O1->P0[1024..2047]
    {
        #pragma unroll
        for (int q = 0; q < 16; ++q) wl[q] = wv[q];
        const float4* X4 = (const float4*)rowIn;           // 1024 chunks
        const int k0 = tid * 8;
        {   // half A: points k0..k0+3, window xw[i]=x[(16tid-16+i)&4095], i=0..23
            float xw[24];
            #pragma unroll
            for (int j = 0; j < 6; ++j) LD4(xw, 4*j, X4[(4*tid - 4 + j) & 1023]);
            float d[4], a[4];
            #pragma unroll
            for (int p = 0; p < 4; ++p) fwd_pt2(&xw[16 + 2*p], &xw[17 + 2*p], wl, d[p], a[p]);
            *(float4*)(crow + k0) = make_float4(d[0], d[1], d[2], d[3]);
            *(float2*)(P0 + (k0 >> 1))        = make_float2(a[0], a[2]);
            *(float2*)(P0 + 1024 + (k0 >> 1)) = make_float2(a[1], a[3]);
        }
        {   // half B: points k0+4..k0+7, window xw[i]=x[(16tid-8+i)&4095]
            float xw[24];
            #pragma unroll
            for (int j = 0; j < 6; ++j) LD4(xw, 4*j, X4[(4*tid - 2 + j) & 1023]);
            float d[4], a[4];
            #pragma unroll
            for (int p = 0; p < 4; ++p) fwd_pt2(&xw[16 + 2*p], &xw[17 + 2*p], wl, d[p], a[p]);
            *(float4*)(crow + k0 + 4) = make_float4(d[0], d[1], d[2], d[3]);
            *(float2*)(P0 + (k0 >> 1) + 2)        = make_float2(a[0], a[2]);
            *(float2*)(P0 + 1024 + (k0 >> 1) + 2) = make_float2(a[1], a[3]);
        }
    }
    __syncthreads();

    // ===== fwd level 1: P0 -> det1(global), E2->P1[0..511], O2->P1[512..1023]
    {
        #pragma unroll
        for (int q = 0; q < 16; ++q) wl[q] = wv[16 + q];
        const float4* E4 = (const float4*)P0;              // 256 chunks
        const float4* O4 = (const float4*)(P0 + 1024);
        float xe[12], xo[12];
        #pragma unroll
        for (int j = 0; j < 3; ++j) {
            int idx = (tid - 2 + j) & 255;
            LD4(xe, 4*j, E4[idx]); LD4(xo, 4*j, O4[idx]);
        }
        float d[4], a[4];
        #pragma unroll
        for (int p = 0; p < 4; ++p) fwd_pt(&xe[8 + p], &xo[8 + p], wl, d[p], a[p]);
        const int k0 = tid * 4;
        *(float4*)(crow + 2048 + k0) = make_float4(d[0], d[1], d[2], d[3]);
        *(float2*)(P1 + (k0 >> 1))       = make_float2(a[0], a[2]);
        *(float2*)(P1 + 512 + (k0 >> 1)) = make_float2(a[1], a[3]);
    }
    __syncthreads();

    // ===== fwd level 2: P1 -> det2(global), E3->P0[0..255], O3->P0[256..511]
    {
        #pragma unroll
        for (int q = 0; q < 16; ++q) wl[q] = wv[32 + q];
        const float2* Ev = (const float2*)P1;              // 256 chunks
        const float2* Ov = (const float2*)(P1 + 512);
        float xe[10], xo[10];
        #pragma unroll
        for (int j = 0; j < 5; ++j) {
            int idx = (tid - 4 + j) & 255;
            LD2(xe, 2*j, Ev[idx]); LD2(xo, 2*j, Ov[idx]);
        }
        float d[2], a[2];
        #pragma unroll
        for (int p = 0; p < 2; ++p) fwd_pt(&xe[8 + p], &xo[8 + p], wl, d[p], a[p]);
        const int k0 = tid * 2;
        *(float2*)(crow + 3072 + k0) = make_float2(d[0], d[1]);
        P0[tid]       = a[0];
        P0[256 + tid] = a[1];
    }
    __syncthreads();

    // ===== middle: wave 0 only, wave-synchronous (fenced, no block barriers) =====
    if (tid < 64) {
        // forward levels 3..7
        const float* Ein = P0;         // E@Ein[0..part-1], O@Ein[part..2*part-1]
        float* aout = P0 + 512;
        int part = 256, cs = 0, cg = 3584;
        for (int lvl = 3; lvl < 8; ++lvl) {
            #pragma unroll
            for (int q = 0; q < 16; ++q) wl[q] = wv[16*lvl + q];
            const int nth = part >> 2;
            if (tid < nth) {
                const int pm = nth - 1;
                const float4* E4 = (const float4*)Ein;
                const float4* O4 = (const float4*)(Ein + part);
                float xe[12], xo[12];
                #pragma unroll
                for (int j = 0; j < 3; ++j) {
                    int idx = (tid - 2 + j) & pm;
                    LD4(xe, 4*j, E4[idx]); LD4(xo, 4*j, O4[idx]);
                }
                float d[4], a[4];
                #pragma unroll
                for (int p = 0; p < 4; ++p) fwd_pt(&xe[8 + p], &xo[8 + p], wl, d[p], a[p]);
                const int k0 = tid * 4;
                float4 dv = make_float4(d[0], d[1], d[2], d[3]);
                *(float4*)(Csm + cs + k0)  = dv;
                *(float4*)(crow + cg + k0) = dv;
                if (lvl == 7) {
                    float4 av = make_float4(a[0], a[1], a[2], a[3]);
                    *(float4*)(Csm + 496 + k0)   = av;
                    *(float4*)(crow + 4080 + k0) = av;
                } else {
                    *(float2*)(aout + (k0 >> 1))               = make_float2(a[0], a[2]);
                    *(float2*)(aout + (part >> 1) + (k0 >> 1)) = make_float2(a[1], a[3]);
                }
            }
            WAVE_FENCE();
            Ein = aout; aout += part; cs += part; cg += part; part >>= 1;
        }
        // backward levels 7..3 -> A3 ends at P0[1504..2015]
        const float* A = Csm + 496;
        float* outp = P0 + 1024;
        int md = 16, dOff = 480;
        for (int lvl = 7; lvl >= 3; --lvl) {
            #pragma unroll
            for (int q = 0; q < 16; ++q) wl[q] = wv[16*lvl + q];
            const int nth = md >> 2;
            if (tid < nth) {
                const int pm = nth - 1;
                const float4* D4 = (const float4*)(Csm + dOff);
                const float4* A4 = (const float4*)A;
                float xd[12], xa[12];
                #pragma unroll
                for (int j = 0; j < 3; ++j) {
                    int idx = (tid - 2 + j) & pm;
                    LD4(xd, 4*j, D4[idx]); LD4(xa, 4*j, A4[idx]);
                }
                float r0[4], r1[4];
                #pragma unroll
                for (int p = 0; p < 4; ++p) bwd_pt(&xd[8 + p], &xa[8 + p], wl, r0[p], r1[p]);
                const int j0 = tid * 4;
                ((float4*)(outp + 2*j0))[0] = make_float4(r0[0], r1[0], r0[1], r1[1]);
                ((float4*)(outp + 2*j0))[1] = make_float4(r0[2], r1[2], r0[3], r1[3]);
            }
            WAVE_FENCE();
            A = outp; outp += 2*md; md <<= 1; dOff -= md;
        }
    }
    __syncthreads();

    // ===== bwd level 2: D=det2(global), A=P0[1504..2015] -> P0[0..1023]
    {
        #pragma unroll
        for (int q = 0; q < 16; ++q) wl[q] = wv[32 + q];
        const float2* Dg = (const float2*)(crow + 3072);   // 256 chunks
        const float2* Av = (const float2*)(P0 + 1504);
        float xd[10], xa[10];
        #pragma unroll
        for (int j = 0; j < 5; ++j) {
            int idx = (tid - 4 + j) & 255;
            LD2(xd, 2*j, Dg[idx]); LD2(xa, 2*j, Av[idx]);
        }
        float r0[2], r1[2];
        #pragma unroll
        for (int p = 0; p < 2; ++p) bwd_pt(&xd[8 + p], &xa[8 + p], wl, r0[p], r1[p]);
        const int j0 = tid * 2;
        *(float4*)(P0 + 2*j0) = make_float4(r0[0], r1[0], r0[1], r1[1]);
    }
    __syncthreads();

    // ===== bwd level 1: D=det1(global), A=P0[0..1023] -> P1[0..2047]
    {
        #pragma unroll
        for (int q = 0; q < 16; ++q) wl[q] = wv[16 + q];
        const float4* Dg = (const float4*)(crow + 2048);   // 256 chunks
        const float4* Av = (const float4*)P0;
        float xd[12], xa[12];
        #pragma unroll
        for (int j = 0; j < 3; ++j) {
            int idx = (tid - 2 + j) & 255;
            LD4(xd, 4*j, Dg[idx]); LD4(xa, 4*j, Av[idx]);
        }
        float r0[4], r1[4];
        #pragma unroll
        for (int p = 0; p < 4; ++p) bwd_pt(&xd[8 + p], &xa[8 + p], wl, r0[p], r1[p]);
        const int j0 = tid * 4;
        ((float4*)(P1 + 2*j0))[0] = make_float4(r0[0], r1[0], r0[1], r1[1]);
        ((float4*)(P1 + 2*j0))[1] = make_float4(r0[2], r1[2], r0[3], r1[3]);
    }
    __syncthreads();

    // ===== bwd level 0: D=det0(global), A=P1 -> rec(global), two halves
    {
        #pragma unroll
        for (int q = 0; q < 16; ++q) wl[q] = wv[q];
        const float4* Dg = (const float4*)crow;            // 512 chunks
        const float4* Av = (const float4*)P1;
        const int j0 = tid * 8;
        {   // half A: j = j0..j0+3, window xd[i]=D[(8tid-8+i)&2047], i=0..11
            float xd[12], xa[12];
            #pragma unroll
            for (int c = 0; c < 3; ++c) {
                int idx = (2*tid - 2 + c) & 511;
                LD4(xd, 4*c, Dg[idx]); LD4(xa, 4*c, Av[idx]);
            }
            float r0[4], r1[4];
            #pragma unroll
            for (int p = 0; p < 4; ++p) bwd_pt(&xd[8 + p], &xa[8 + p], wl, r0[p], r1[p]);
            ((float4*)(rrow + 2*j0))[0] = make_float4(r0[0], r1[0], r0[1], r1[1]);
            ((float4*)(rrow + 2*j0))[1] = make_float4(r0[2], r1[2], r0[3], r1[3]);
        }
        {   // half B: j = j0+4..j0+7, window xd[i]=D[(8tid-4+i)&2047]
            float xd[12], xa[12];
            #pragma unroll
            for (int c = 0; c < 3; ++c) {
                int idx = (2*tid - 1 + c) & 511;
                LD4(xd, 4*c, Dg[idx]); LD4(xa, 4*c, Av[idx]);
            }
            float r0[4], r1[4];
            #pragma unroll
            for (int p = 0; p < 4; ++p) bwd_pt(&xd[8 + p], &xa[8 + p], wl, r0[p], r1[p]);
            ((float4*)(rrow + 2*j0))[2] = make_float4(r0[0], r1[0], r0[1], r1[1]);
            ((float4*)(rrow + 2*j0))[3] = make_float4(r0[2], r1[2], r0[3], r1[3]);
        }
    }
}

extern "C" void kernel_launch(void* const* d_in, const int* in_sizes, int n_in,
                              void* d_out, int out_size, void* d_ws, size_t ws_size,
                              hipStream_t stream) {
    (void)in_sizes; (void)n_in; (void)d_ws; (void)ws_size; (void)out_size;
    const float* in = (const float*)d_in[0];
    const float* wv = (const float*)d_in[1];
    float* out_rec  = (float*)d_out;
    float* out_coef = (float*)d_out + (size_t)NROWS * NCOLS;
    despawn_kernel<<<NROWS, TPB, 0, stream>>>(in, wv, out_rec, out_coef);
}

// Round 7
// 56.532 us; speedup vs baseline: 1.0053x; 1.0053x over previous
//
#include <hip/hip_runtime.h>

#define NROWS 4096
#define NCOLS 4096
#define TPB   256

// Global coeff row layout (floats):
// [det0 2048 | det1 1024 | det2 512 | det3 256 | det4 128 | det5 64 | det6 32 | det7 16 | a7 16]
// LDS (28 KB): P0[2048] work ping, P1[1024] work pong, Csm[512] dets3..7+a7,
//              D0[2048], D1[1024], D2[512] det mirrors (bwd reads LDS, not HBM).

#define LD4(arr, base, vec) { float4 _v = (vec); (arr)[(base)] = _v.x; (arr)[(base)+1] = _v.y; (arr)[(base)+2] = _v.z; (arr)[(base)+3] = _v.w; }
#define LD2(arr, base, vec) { float2 _v = (vec); (arr)[(base)] = _v.x; (arr)[(base)+1] = _v.y; }

// stride-1 taps: E/O are separate (deinterleaved) arrays
__device__ __forceinline__ void fwd_pt(const float* e8, const float* o8,
                                       const float* wl, float& dd, float& aa)
{
    float d = 0.f, a = 0.f;
    #pragma unroll
    for (int t = 0; t < 8; ++t) {
        float e = e8[-t], o = o8[-t];
        d = fmaf(wl[2*t],     e, d);
        d = fmaf(wl[2*t+1],   o, d);
        a = fmaf(wl[15-2*t],  e, a);
        a = fmaf(-wl[14-2*t], o, a);
    }
    dd = d; aa = a;
}

// stride-2 taps: window is the RAW interleaved x row (E[k-t]=x[2(k-t)])
__device__ __forceinline__ void fwd_pt2(const float* e8, const float* o8,
                                        const float* wl, float& dd, float& aa)
{
    float d = 0.f, a = 0.f;
    #pragma unroll
    for (int t = 0; t < 8; ++t) {
        float e = e8[-2*t], o = o8[-2*t];
        d = fmaf(wl[2*t],     e, d);
        d = fmaf(wl[2*t+1],   o, d);
        a = fmaf(wl[15-2*t],  e, a);
        a = fmaf(-wl[14-2*t], o, a);
    }
    dd = d; aa = a;
}

__device__ __forceinline__ void bwd_pt(const float* d8, const float* a8,
                                       const float* wl, float& rr0, float& rr1)
{
    float x = 0.f, y = 0.f;
    #pragma unroll
    for (int t = 0; t < 8; ++t) {
        float dv = d8[-t], av = a8[-t];
        x = fmaf(wl[15-2*t], dv, x);
        x = fmaf(wl[2*t],    av, x);
        y = fmaf(wl[14-2*t], dv, y);
        y = fmaf(-wl[2*t+1], av, y);
    }
    rr0 = x; rr1 = y;
}

__global__ __launch_bounds__(TPB, 5) void despawn_kernel(
    const float* __restrict__ in, const float* __restrict__ wv,
    float* __restrict__ out_rec, float* __restrict__ out_coef)
{
    __shared__ float P0[2048];
    __shared__ float P1[1024];
    __shared__ float Csm[512];
    __shared__ float D0[2048];
    __shared__ float D1[1024];
    __shared__ float D2[512];

    const int tid = threadIdx.x;
    const int row = blockIdx.x;
    const float* rowIn = in + (size_t)row * NCOLS;
    float* crow = out_coef + (size_t)row * NCOLS;
    float* rrow = out_rec  + (size_t)row * NCOLS;

    float wl[16];

    // ===== fwd level 0: global x -> det0 (global+D0), E1->P0[0..1023], O1->P0[1024..2047]
    {
        #pragma unroll
        for (int q = 0; q < 16; ++q) wl[q] = wv[q];
        const float4* X4 = (const float4*)rowIn;           // 1024 chunks
        float xw[32];                                      // x[(16tid-16+i)&4095], i=0..31
        #pragma unroll
        for (int j = 0; j < 8; ++j) LD4(xw, 4*j, X4[(4*tid - 4 + j) & 1023]);
        float d[8], a[8];
        #pragma unroll
        for (int p = 0; p < 8; ++p) fwd_pt2(&xw[16 + 2*p], &xw[17 + 2*p], wl, d[p], a[p]);
        const int k0 = tid * 8;
        float4 d0v = make_float4(d[0], d[1], d[2], d[3]);
        float4 d1v = make_float4(d[4], d[5], d[6], d[7]);
        ((float4*)(crow + k0))[0] = d0v;
        ((float4*)(crow + k0))[1] = d1v;
        ((float4*)(D0 + k0))[0]   = d0v;
        ((float4*)(D0 + k0))[1]   = d1v;
        *(float4*)(P0 + (k0 >> 1))        = make_float4(a[0], a[2], a[4], a[6]);  // E1
        *(float4*)(P0 + 1024 + (k0 >> 1)) = make_float4(a[1], a[3], a[5], a[7]);  // O1
    }
    __syncthreads();

    // ===== fwd level 1: P0 -> det1 (global+D1), E2->P1[0..511], O2->P1[512..1023]
    {
        #pragma unroll
        for (int q = 0; q < 16; ++q) wl[q] = wv[16 + q];
        const float4* E4 = (const float4*)P0;              // 256 chunks
        const float4* O4 = (const float4*)(P0 + 1024);
        float xe[12], xo[12];
        #pragma unroll
        for (int j = 0; j < 3; ++j) {
            int idx = (tid - 2 + j) & 255;
            LD4(xe, 4*j, E4[idx]); LD4(xo, 4*j, O4[idx]);
        }
        float d[4], a[4];
        #pragma unroll
        for (int p = 0; p < 4; ++p) fwd_pt(&xe[8 + p], &xo[8 + p], wl, d[p], a[p]);
        const int k0 = tid * 4;
        float4 dv = make_float4(d[0], d[1], d[2], d[3]);
        *(float4*)(crow + 2048 + k0) = dv;
        *(float4*)(D1 + k0)          = dv;
        *(float2*)(P1 + (k0 >> 1))       = make_float2(a[0], a[2]);
        *(float2*)(P1 + 512 + (k0 >> 1)) = make_float2(a[1], a[3]);
    }
    __syncthreads();

    // ===== fwd level 2: P1 -> det2 (global+D2), E3->P0[0..255], O3->P0[256..511]
    {
        #pragma unroll
        for (int q = 0; q < 16; ++q) wl[q] = wv[32 + q];
        const float2* Ev = (const float2*)P1;              // 256 chunks
        const float2* Ov = (const float2*)(P1 + 512);
        float xe[10], xo[10];
        #pragma unroll
        for (int j = 0; j < 5; ++j) {
            int idx = (tid - 4 + j) & 255;
            LD2(xe, 2*j, Ev[idx]); LD2(xo, 2*j, Ov[idx]);
        }
        float d[2], a[2];
        #pragma unroll
        for (int p = 0; p < 2; ++p) fwd_pt(&xe[8 + p], &xo[8 + p], wl, d[p], a[p]);
        const int k0 = tid * 2;
        float2 dv = make_float2(d[0], d[1]);
        *(float2*)(crow + 3072 + k0) = dv;
        *(float2*)(D2 + k0)          = dv;
        P0[tid]       = a[0];
        P0[256 + tid] = a[1];
    }
    __syncthreads();

    // ===== fwd levels 3..7: bump-allocated in P0[512..1023], dets -> Csm + global
    {
        const float* Ein = P0;         // E@Ein[0..part-1], O@Ein[part..2*part-1]
        float* aout = P0 + 512;
        int part = 256, cs = 0, cg = 3584;
        for (int lvl = 3; lvl < 8; ++lvl) {
            #pragma unroll
            for (int q = 0; q < 16; ++q) wl[q] = wv[16*lvl + q];
            const int nth = part >> 2;
            if (tid < nth) {
                const int pm = nth - 1;
                const float4* E4 = (const float4*)Ein;
                const float4* O4 = (const float4*)(Ein + part);
                float xe[12], xo[12];
                #pragma unroll
                for (int j = 0; j < 3; ++j) {
                    int idx = (tid - 2 + j) & pm;
                    LD4(xe, 4*j, E4[idx]); LD4(xo, 4*j, O4[idx]);
                }
                float d[4], a[4];
                #pragma unroll
                for (int p = 0; p < 4; ++p) fwd_pt(&xe[8 + p], &xo[8 + p], wl, d[p], a[p]);
                const int k0 = tid * 4;
                float4 dv = make_float4(d[0], d[1], d[2], d[3]);
                *(float4*)(Csm + cs + k0)  = dv;
                *(float4*)(crow + cg + k0) = dv;
                if (lvl == 7) {
                    float4 av = make_float4(a[0], a[1], a[2], a[3]);
                    *(float4*)(Csm + 496 + k0)   = av;
                    *(float4*)(crow + 4080 + k0) = av;
                } else {
                    *(float2*)(aout + (k0 >> 1))               = make_float2(a[0], a[2]);
                    *(float2*)(aout + (part >> 1) + (k0 >> 1)) = make_float2(a[1], a[3]);
                }
            }
            __syncthreads();
            Ein = aout; aout += part; cs += part; cg += part; part >>= 1;
        }
    }

    // ===== bwd levels 7..3: Csm -> bump P0[1024..2015]; A3 = P0[1504..2015]
    const float* A = Csm + 496;   // a7
    {
        float* outp = P0 + 1024;
        int md = 16, dOff = 480;
        for (int lvl = 7; lvl >= 3; --lvl) {
            #pragma unroll
            for (int q = 0; q < 16; ++q) wl[q] = wv[16*lvl + q];
            const int nth = md >> 2;
            if (tid < nth) {
                const int pm = nth - 1;
                const float4* D4 = (const float4*)(Csm + dOff);
                const float4* A4 = (const float4*)A;
                float xd[12], xa[12];
                #pragma unroll
                for (int j = 0; j < 3; ++j) {
                    int idx = (tid - 2 + j) & pm;
                    LD4(xd, 4*j, D4[idx]); LD4(xa, 4*j, A4[idx]);
                }
                float r0[4], r1[4];
                #pragma unroll
                for (int p = 0; p < 4; ++p) bwd_pt(&xd[8 + p], &xa[8 + p], wl, r0[p], r1[p]);
                const int j0 = tid * 4;
                ((float4*)(outp + 2*j0))[0] = make_float4(r0[0], r1[0], r0[1], r1[1]);
                ((float4*)(outp + 2*j0))[1] = make_float4(r0[2], r1[2], r0[3], r1[3]);
            }
            __syncthreads();
            A = outp; outp += 2*md; md <<= 1; dOff -= md;
        }
    }

    // ===== bwd level 2: D=D2(LDS), A=P0[1504..2015] -> P1[0..1023]
    {
        #pragma unroll
        for (int q = 0; q < 16; ++q) wl[q] = wv[32 + q];
        const float2* Dg = (const float2*)D2;              // 256 chunks
        const float2* Av = (const float2*)(P0 + 1504);
        float xd[10], xa[10];
        #pragma unroll
        for (int j = 0; j < 5; ++j) {
            int idx = (tid - 4 + j) & 255;
            LD2(xd, 2*j, Dg[idx]); LD2(xa, 2*j, Av[idx]);
        }
        float r0[2], r1[2];
        #pragma unroll
        for (int p = 0; p < 2; ++p) bwd_pt(&xd[8 + p], &xa[8 + p], wl, r0[p], r1[p]);
        const int j0 = tid * 2;
        *(float4*)(P1 + 2*j0) = make_float4(r0[0], r1[0], r0[1], r1[1]);
    }
    __syncthreads();

    // ===== bwd level 1: D=D1(LDS), A=P1[0..1023] -> P0[0..2047]
    {
        #pragma unroll
        for (int q = 0; q < 16; ++q) wl[q] = wv[16 + q];
        const float4* Dg = (const float4*)D1;              // 256 chunks
        const float4* Av = (const float4*)P1;
        float xd[12], xa[12];
        #pragma unroll
        for (int j = 0; j < 3; ++j) {
            int idx = (tid - 2 + j) & 255;
            LD4(xd, 4*j, Dg[idx]); LD4(xa, 4*j, Av[idx]);
        }
        float r0[4], r1[4];
        #pragma unroll
        for (int p = 0; p < 4; ++p) bwd_pt(&xd[8 + p], &xa[8 + p], wl, r0[p], r1[p]);
        const int j0 = tid * 4;
        ((float4*)(P0 + 2*j0))[0] = make_float4(r0[0], r1[0], r0[1], r1[1]);
        ((float4*)(P0 + 2*j0))[1] = make_float4(r0[2], r1[2], r0[3], r1[3]);
    }
    __syncthreads();

    // ===== bwd level 0: D=D0(LDS), A=P0 -> rec(global), two halves
    {
        #pragma unroll
        for (int q = 0; q < 16; ++q) wl[q] = wv[q];
        const float4* Dg = (const float4*)D0;              // 512 chunks
        const float4* Av = (const float4*)P0;
        const int j0 = tid * 8;
        {   // half A: j = j0..j0+3
            float xd[12], xa[12];
            #pragma unroll
            for (int c = 0; c < 3; ++c) {
                int idx = (2*tid - 2 + c) & 511;
                LD4(xd, 4*c, Dg[idx]); LD4(xa, 4*c, Av[idx]);
            }
            float r0[4], r1[4];
            #pragma unroll
            for (int p = 0; p < 4; ++p) bwd_pt(&xd[8 + p], &xa[8 + p], wl, r0[p], r1[p]);
            ((float4*)(rrow + 2*j0))[0] = make_float4(r0[0], r1[0], r0[1], r1[1]);
            ((float4*)(rrow + 2*j0))[1] = make_float4(r0[2], r1[2], r0[3], r1[3]);
        }
        {   // half B: j = j0+4..j0+7
            float xd[12], xa[12];
            #pragma unroll
            for (int c = 0; c < 3; ++c) {
                int idx = (2*tid - 1 + c) & 511;
                LD4(xd, 4*c, Dg[idx]); LD4(xa, 4*c, Av[idx]);
            }
            float r0[4], r1[4];
            #pragma unroll
            for (int p = 0; p < 4; ++p) bwd_pt(&xd[8 + p], &xa[8 + p], wl, r0[p], r1[p]);
            ((float4*)(rrow + 2*j0))[2] = make_float4(r0[0], r1[0], r0[1], r1[1]);
            ((float4*)(rrow + 2*j0))[3] = make_float4(r0[2], r1[2], r0[3], r1[3]);
        }
    }
}

extern "C" void kernel_launch(void* const* d_in, const int* in_sizes, int n_in,
                              void* d_out, int out_size, void* d_ws, size_t ws_size,
                              hipStream_t stream) {
    (void)in_sizes; (void)n_in; (void)d_ws; (void)ws_size; (void)out_size;
    const float* in = (const float*)d_in[0];
    const float* wv = (const float*)d_in[1];
    float* out_rec  = (float*)d_out;
    float* out_coef = (float*)d_out + (size_t)NROWS * NCOLS;
    despawn_kernel<<<NROWS, TPB, 0, stream>>>(in, wv, out_rec, out_coef);
}

// Round 8
// 55.749 us; speedup vs baseline: 1.0195x; 1.0140x over previous
//
#include <hip/hip_runtime.h>

#define NROWS 4096
#define NCOLS 4096
#define TPB   256

// Global coeff row layout (floats):
// [det0 2048 | det1 1024 | det2 512 | det3 256 | det4 128 | det5 64 | det6 32 | det7 16 | a7 16]
//
// LDS (18.3 KB):
//  W0[2048]: fwd E1|O1; bwd Re1(1024)|Ro1(1024)
//  W1[1024]: fwd E2|O2; bwd Re2(512)|Ro2(512)
//  U[992]  : fwd E3|O3(512), E4|O4(256), E5|O5(128), E6|O6(64), E7|O7(32)  [bump]
//            bwd rec7(32) rec6(64) rec5(128) rec4(256) rec3(512), each split Re|Ro [bump]
//  Csm[512]: det3(256) det4(128) det5(64) det6(32) det7(16) a7e(8) a7o(8)
//
// ALL bwd rec arrays are parity-split (Re[j]=rec[2j], Ro[j]=rec[2j+1]) so every
// LDS access is 16B/8B/4B lane-stride = bank-conflict-free. Parity selection of
// A[(j-s) mod md] happens in registers with static indices after unroll.

#define LD4(arr, base, vec) { float4 _v = (vec); (arr)[(base)] = _v.x; (arr)[(base)+1] = _v.y; (arr)[(base)+2] = _v.z; (arr)[(base)+3] = _v.w; }
#define LD2(arr, base, vec) { float2 _v = (vec); (arr)[(base)] = _v.x; (arr)[(base)+1] = _v.y; }

// stride-1 taps: E/O are separate (deinterleaved) arrays
__device__ __forceinline__ void fwd_pt(const float* e8, const float* o8,
                                       const float* wl, float& dd, float& aa)
{
    float d = 0.f, a = 0.f;
    #pragma unroll
    for (int t = 0; t < 8; ++t) {
        float e = e8[-t], o = o8[-t];
        d = fmaf(wl[2*t],     e, d);
        d = fmaf(wl[2*t+1],   o, d);
        a = fmaf(wl[15-2*t],  e, a);
        a = fmaf(-wl[14-2*t], o, a);
    }
    dd = d; aa = a;
}

// stride-2 taps: window is the RAW interleaved x row (E[k-t]=x[2(k-t)])
__device__ __forceinline__ void fwd_pt2(const float* e8, const float* o8,
                                        const float* wl, float& dd, float& aa)
{
    float d = 0.f, a = 0.f;
    #pragma unroll
    for (int t = 0; t < 8; ++t) {
        float e = e8[-2*t], o = o8[-2*t];
        d = fmaf(wl[2*t],     e, d);
        d = fmaf(wl[2*t+1],   o, d);
        a = fmaf(wl[15-2*t],  e, a);
        a = fmaf(-wl[14-2*t], o, a);
    }
    dd = d; aa = a;
}

// bwd point with split-A: xd = natural D window (xd[8+p-s] = D[j+p-s]);
// ae[q] = A[base+2q], ao[q] = A[base+1+2q] where base = j0-8 (so m=p-s+8).
template<int NP>
__device__ __forceinline__ void bwd_split(const float* xd, const float* ae, const float* ao,
                                          const float* wl, float* r0, float* r1)
{
    #pragma unroll
    for (int p = 0; p < NP; ++p) {
        float x = 0.f, y = 0.f;
        #pragma unroll
        for (int s = 0; s < 8; ++s) {
            float dv = xd[8 + p - s];
            const int m = p - s + 8;
            float av = (m & 1) ? ao[(m - 1) >> 1] : ae[m >> 1];
            x = fmaf(wl[15-2*s], dv, x);
            x = fmaf(wl[2*s],    av, x);
            y = fmaf(wl[14-2*s], dv, y);
            y = fmaf(-wl[2*s+1], av, y);
        }
        r0[p] = x; r1[p] = y;
    }
}

__global__ __launch_bounds__(TPB, 7) void despawn_kernel(
    const float* __restrict__ in, const float* __restrict__ wv,
    float* __restrict__ out_rec, float* __restrict__ out_coef)
{
    __shared__ float W0[2048];
    __shared__ float W1[1024];
    __shared__ float U[992];
    __shared__ float Csm[512];

    const int tid = threadIdx.x;
    const int row = blockIdx.x;
    const float* rowIn = in + (size_t)row * NCOLS;
    float* crow = out_coef + (size_t)row * NCOLS;
    float* rrow = out_rec  + (size_t)row * NCOLS;

    float wl[16];

    // ===== fwd level 0: global x -> det0(global), E1->W0[0..1023], O1->W0[1024..2047]
    {
        #pragma unroll
        for (int q = 0; q < 16; ++q) wl[q] = wv[q];
        const float4* X4 = (const float4*)rowIn;           // 1024 chunks
        float xw[32];                                      // x[(16tid-16+i)&4095]
        #pragma unroll
        for (int j = 0; j < 8; ++j) LD4(xw, 4*j, X4[(4*tid - 4 + j) & 1023]);
        float d[8], a[8];
        #pragma unroll
        for (int p = 0; p < 8; ++p) fwd_pt2(&xw[16 + 2*p], &xw[17 + 2*p], wl, d[p], a[p]);
        const int k0 = tid * 8;
        ((float4*)(crow + k0))[0] = make_float4(d[0], d[1], d[2], d[3]);
        ((float4*)(crow + k0))[1] = make_float4(d[4], d[5], d[6], d[7]);
        *(float4*)(W0 + (k0 >> 1))        = make_float4(a[0], a[2], a[4], a[6]);  // E1
        *(float4*)(W0 + 1024 + (k0 >> 1)) = make_float4(a[1], a[3], a[5], a[7]);  // O1
    }
    __syncthreads();

    // ===== fwd level 1: W0 -> det1(global), E2->W1[0..511], O2->W1[512..1023]
    {
        #pragma unroll
        for (int q = 0; q < 16; ++q) wl[q] = wv[16 + q];
        const float4* E4 = (const float4*)W0;              // 256 chunks
        const float4* O4 = (const float4*)(W0 + 1024);
        float xe[12], xo[12];
        #pragma unroll
        for (int j = 0; j < 3; ++j) {
            int idx = (tid - 2 + j) & 255;
            LD4(xe, 4*j, E4[idx]); LD4(xo, 4*j, O4[idx]);
        }
        float d[4], a[4];
        #pragma unroll
        for (int p = 0; p < 4; ++p) fwd_pt(&xe[8 + p], &xo[8 + p], wl, d[p], a[p]);
        const int k0 = tid * 4;
        *(float4*)(crow + 2048 + k0) = make_float4(d[0], d[1], d[2], d[3]);
        *(float2*)(W1 + (k0 >> 1))       = make_float2(a[0], a[2]);
        *(float2*)(W1 + 512 + (k0 >> 1)) = make_float2(a[1], a[3]);
    }
    __syncthreads();

    // ===== fwd level 2: W1 -> det2(global), E3->U[0..255], O3->U[256..511]
    {
        #pragma unroll
        for (int q = 0; q < 16; ++q) wl[q] = wv[32 + q];
        const float2* Ev = (const float2*)W1;              // 256 chunks
        const float2* Ov = (const float2*)(W1 + 512);
        float xe[10], xo[10];
        #pragma unroll
        for (int j = 0; j < 5; ++j) {
            int idx = (tid - 4 + j) & 255;
            LD2(xe, 2*j, Ev[idx]); LD2(xo, 2*j, Ov[idx]);
        }
        float d[2], a[2];
        #pragma unroll
        for (int p = 0; p < 2; ++p) fwd_pt(&xe[8 + p], &xo[8 + p], wl, d[p], a[p]);
        const int k0 = tid * 2;
        *(float2*)(crow + 3072 + k0) = make_float2(d[0], d[1]);
        U[tid]       = a[0];
        U[256 + tid] = a[1];
    }
    __syncthreads();

    // ===== fwd levels 3..7: bump in U, dets -> Csm + global; lvl7 a7 split into Csm
    {
        const float* Ein = U;          // E@Ein[0..part-1], O@Ein[part..2*part-1]
        float* aout = U + 512;
        int part = 256, cs = 0, cg = 3584;
        for (int lvl = 3; lvl < 8; ++lvl) {
            #pragma unroll
            for (int q = 0; q < 16; ++q) wl[q] = wv[16*lvl + q];
            const int nth = part >> 2;
            if (tid < nth) {
                const int pm = nth - 1;
                const float4* E4 = (const float4*)Ein;
                const float4* O4 = (const float4*)(Ein + part);
                float xe[12], xo[12];
                #pragma unroll
                for (int j = 0; j < 3; ++j) {
                    int idx = (tid - 2 + j) & pm;
                    LD4(xe, 4*j, E4[idx]); LD4(xo, 4*j, O4[idx]);
                }
                float d[4], a[4];
                #pragma unroll
                for (int p = 0; p < 4; ++p) fwd_pt(&xe[8 + p], &xo[8 + p], wl, d[p], a[p]);
                const int k0 = tid * 4;
                float4 dv = make_float4(d[0], d[1], d[2], d[3]);
                *(float4*)(Csm + cs + k0)  = dv;
                *(float4*)(crow + cg + k0) = dv;
                if (lvl == 7) {
                    *(float4*)(crow + 4080 + k0) = make_float4(a[0], a[1], a[2], a[3]);
                    *(float2*)(Csm + 496 + 2*tid) = make_float2(a[0], a[2]);  // a7e
                    *(float2*)(Csm + 504 + 2*tid) = make_float2(a[1], a[3]);  // a7o
                } else {
                    *(float2*)(aout + (k0 >> 1))               = make_float2(a[0], a[2]);
                    *(float2*)(aout + (part >> 1) + (k0 >> 1)) = make_float2(a[1], a[3]);
                }
            }
            __syncthreads();
            Ein = aout; aout += part; cs += part; cg += part; part >>= 1;
        }
    }

    // ===== bwd levels 7..3: D from Csm, A split; rec split -> U bump
    const float* AeP = Csm + 496;   // a7e
    const float* AoP = Csm + 504;   // a7o
    {
        float* uout = U;
        int md = 16, dOff = 480;
        for (int lvl = 7; lvl >= 3; --lvl) {
            #pragma unroll
            for (int q = 0; q < 16; ++q) wl[q] = wv[16*lvl + q];
            const int nth = md >> 2;
            if (tid < nth) {
                const int pm = nth - 1;
                const float4* D4 = (const float4*)(Csm + dOff);
                float xd[12];
                #pragma unroll
                for (int j = 0; j < 3; ++j) LD4(xd, 4*j, D4[(tid - 2 + j) & pm]);
                // A windows: ae[q]=A[4t-8+2q], ao[q]=A[4t-7+2q]  (float2 chunks, mask pm)
                float ae[6], ao[6];
                #pragma unroll
                for (int c = 0; c < 3; ++c) {
                    int idx = (tid - 2 + c) & pm;
                    LD2(ae, 2*c, ((const float2*)AeP)[idx]);
                    LD2(ao, 2*c, ((const float2*)AoP)[idx]);
                }
                float r0[4], r1[4];
                bwd_split<4>(xd, ae, ao, wl, r0, r1);
                *(float4*)(uout + 4*tid)      = make_float4(r0[0], r0[1], r0[2], r0[3]); // Re
                *(float4*)(uout + md + 4*tid) = make_float4(r1[0], r1[1], r1[2], r1[3]); // Ro
            }
            __syncthreads();
            AeP = uout; AoP = uout + md;
            uout += 2 * md; md <<= 1; dOff -= md;
        }
    }
    // AeP=U+480 (Re3, 256), AoP=U+736 (Ro3, 256); md now 512

    // ===== bwd level 2: D=det2(global), A=rec3 split -> Re2=W1[0..511], Ro2=W1[512..1023]
    {
        #pragma unroll
        for (int q = 0; q < 16; ++q) wl[q] = wv[32 + q];
        const float2* Dg = (const float2*)(crow + 3072);   // 256 chunks
        float xd[10];
        #pragma unroll
        for (int j = 0; j < 5; ++j) LD2(xd, 2*j, Dg[(tid - 4 + j) & 255]);
        // ae[q]=A[2t-8+2q]=AeP[t-4+q], ao[q]=A[2t-7+2q]=AoP[t-4+q]
        float ae[5], ao[5];
        #pragma unroll
        for (int q = 0; q < 5; ++q) {
            int idx = (tid - 4 + q) & 255;
            ae[q] = AeP[idx]; ao[q] = AoP[idx];
        }
        float r0[2], r1[2];
        bwd_split<2>(xd, ae, ao, wl, r0, r1);
        *(float2*)(W1 + 2*tid)       = make_float2(r0[0], r0[1]);
        *(float2*)(W1 + 512 + 2*tid) = make_float2(r1[0], r1[1]);
    }
    __syncthreads();

    // ===== bwd level 1: D=det1(global), A=rec2 split -> Re1=W0[0..1023], Ro1=W0[1024..2047]
    {
        #pragma unroll
        for (int q = 0; q < 16; ++q) wl[q] = wv[16 + q];
        const float4* Dg = (const float4*)(crow + 2048);   // 256 chunks
        float xd[12];
        #pragma unroll
        for (int j = 0; j < 3; ++j) LD4(xd, 4*j, Dg[(tid - 2 + j) & 255]);
        // ae[q]=A[4t-8+2q] via float2 chunks (t-2+c)&255 of W1 halves
        float ae[6], ao[6];
        #pragma unroll
        for (int c = 0; c < 3; ++c) {
            int idx = (tid - 2 + c) & 255;
            LD2(ae, 2*c, ((const float2*)W1)[idx]);
            LD2(ao, 2*c, ((const float2*)(W1 + 512))[idx]);
        }
        float r0[4], r1[4];
        bwd_split<4>(xd, ae, ao, wl, r0, r1);
        *(float4*)(W0 + 4*tid)        = make_float4(r0[0], r0[1], r0[2], r0[3]);
        *(float4*)(W0 + 1024 + 4*tid) = make_float4(r1[0], r1[1], r1[2], r1[3]);
    }
    __syncthreads();

    // ===== bwd level 0: D=det0(global), A=rec1 split (W0) -> rec(global)
    {
        #pragma unroll
        for (int q = 0; q < 16; ++q) wl[q] = wv[q];
        const float4* Dg = (const float4*)crow;            // 512 chunks
        float xd[16];                                      // D[8t-8 .. 8t+7]
        #pragma unroll
        for (int c = 0; c < 4; ++c) LD4(xd, 4*c, Dg[(2*tid - 2 + c) & 511]);
        // ae[q]=A[8t-8+2q]=W0[4t-4+q] (q=0..7): float4 chunks (t-1+c)&255
        float ae[8], ao[8];
        #pragma unroll
        for (int c = 0; c < 2; ++c) {
            int idx = (tid - 1 + c) & 255;
            LD4(ae, 4*c, ((const float4*)W0)[idx]);
            LD4(ao, 4*c, ((const float4*)(W0 + 1024))[idx]);
        }
        float r0[8], r1[8];
        bwd_split<8>(xd, ae, ao, wl, r0, r1);
        const int j0 = tid * 8;
        float4* R = (float4*)(rrow + 2*j0);
        R[0] = make_float4(r0[0], r1[0], r0[1], r1[1]);
        R[1] = make_float4(r0[2], r1[2], r0[3], r1[3]);
        R[2] = make_float4(r0[4], r1[4], r0[5], r1[5]);
        R[3] = make_float4(r0[6], r1[6], r0[7], r1[7]);
    }
}

extern "C" void kernel_launch(void* const* d_in, const int* in_sizes, int n_in,
                              void* d_out, int out_size, void* d_ws, size_t ws_size,
                              hipStream_t stream) {
    (void)in_sizes; (void)n_in; (void)d_ws; (void)ws_size; (void)out_size;
    const float* in = (const float*)d_in[0];
    const float* wv = (const float*)d_in[1];
    float* out_rec  = (float*)d_out;
    float* out_coef = (float*)d_out + (size_t)NROWS * NCOLS;
    despawn_kernel<<<NROWS, TPB, 0, stream>>>(in, wv, out_rec, out_coef);
}